// Round 6
// baseline (70.014 us; speedup 1.0000x reference)
//
#include <hip/hip_runtime.h>
#include <stdint.h>

#define KCODES  1024
#define CDIM    64
#define SPATIAL 32768
#define NPOS    65536
#define NEL     4194304

// d_out layout (floats), outputs concatenated in reference return order
#define OUT_Q    0
#define OUT_LOSS 4194304
#define OUT_IDX  4194305
#define OUT_SUM  4259841
#define OUT_EMB  4260097

// ws: 8 chunks x {hi frags 16KB | lo frags 16KB | -0.5*||e||^2 512B}
#define REC_BYTES 33280
#define BPOS 64            // positions per block

typedef _Float16 half8 __attribute__((ext_vector_type(8)));
typedef float    f32x4 __attribute__((ext_vector_type(4)));

// ---- prep: fragment-swizzle codebook, zero loss/sum, emb passthrough (64 blocks) ----
__global__ void prep_emb(const float* __restrict__ emb, char* __restrict__ ws,
                         float* __restrict__ out) {
    int gt = blockIdx.x * 256 + threadIdx.x;        // 0..16383
    if (gt == 0) out[OUT_LOSS] = 0.f;
    if (gt < 256) out[OUT_SUM + gt] = 0.f;
    // embedding passthrough: 4 floats/thread (OUT_EMB is odd -> scalar stores)
    {
        float4 v = *(const float4*)(emb + (size_t)gt * 4);
        float* o = out + OUT_EMB + (size_t)gt * 4;
        o[0] = v.x; o[1] = v.y; o[2] = v.z; o[3] = v.w;
    }
    // fragment swizzle: 8192 threads, one (code, 8-chan octet) each
    if (gt < 8192) {
        int k = gt >> 3, oct = gt & 7;
        int ch = k >> 7, mt = (k >> 4) & 7, row = k & 15;
        int s = oct >> 2, g = oct & 3;              // c = oct*8+i
        const float* e = emb + (size_t)k * CDIM + oct * 8;
        char* rec = ws + (size_t)ch * REC_BYTES;
        _Float16* hi = (_Float16*)rec + (size_t)(mt * 2 + s) * 512 + ((g << 4) | row) * 8;
        _Float16* lo = hi + 8192;
        float s2 = 0.f;
        half8 hv, lv;
#pragma unroll
        for (int i = 0; i < 8; ++i) {
            float v = e[i];
            s2 = fmaf(v, v, s2);
            _Float16 h = (_Float16)v;
            hv[i] = h;
            lv[i] = (_Float16)(v - (float)h);
        }
        *(half8*)hi = hv;
        *(half8*)lo = lv;
        // reduce s2 over the 8-lane octet group (same wave: 8 codes per 64 lanes)
        s2 += __shfl_xor(s2, 1);
        s2 += __shfl_xor(s2, 2);
        s2 += __shfl_xor(s2, 4);
        if (oct == 0) ((float*)(rec + 32768))[k & 127] = -0.5f * s2;
    }
}

// async global->LDS, 16B per lane, dst = wave-uniform base + lane*16
#define GLDS16(GSRC, LDST)                                                     \
    __builtin_amdgcn_global_load_lds(                                          \
        (const __attribute__((address_space(1))) void*)(GSRC),                 \
        (__attribute__((address_space(3))) void*)(LDST), 16, 0, 0)

// ---- main VQ kernel ----
// Block: 256 thr = 4 waves, 64 positions (4 N-tiles of 16 per wave).
// mt-interleaved K-split (wave wv: gmt = wv+4*it). Each wave double-buffers its
// 4KB fragment set in LDS via global_load_lds (zero VGPR prefetch), counted
// vmcnt(5) so next-set loads stay in flight across the consume. No barriers.
// Score = x.e - 0.5||e||^2 (C-init), argmax == argmin distance.
__global__ __launch_bounds__(256, 2) void vq_kernel(
        const float* __restrict__ in, const float* __restrict__ emb,
        const char* __restrict__ wsA, float* __restrict__ out) {
    __shared__ __align__(16) char stg[4][2][4096];   // [wave][dbuf][4KB set]
    __shared__ float xl[CDIM * 65];        // x tile [c][pos], pitch 65 (16640 B)
    __shared__ float redS[4][4][16];       // wave, tile, col
    __shared__ int   redK[4][4][16];
    __shared__ int   kwin[BPOS];

    const int tid  = threadIdx.x;
    const int lane = tid & 63, wv = tid >> 6;
    const int g = lane >> 4, col = lane & 15;
    const int p0 = blockIdx.x * BPOS;
    const int b  = p0 >> 15;               // 64-pos tile never straddles batch
    const int s0 = p0 & 32767;
    const float* xin = in + (size_t)b * (CDIM * SPATIAL) + s0;

    char* const sA = &stg[wv][0][0];
    char* const sB = &stg[wv][1][0];

#define STAGE(GMT, SB) do {                                                    \
        int gmt_ = (GMT);                                                      \
        const char* rec_ = wsA + (size_t)(gmt_ >> 3) * REC_BYTES;              \
        int mt_ = gmt_ & 7;                                                    \
        const char* h_ = rec_ + mt_ * 2048 + (size_t)lane * 16;                \
        GLDS16(h_,         (SB));                                              \
        GLDS16(h_ + 1024,  (SB) + 1024);                                       \
        GLDS16(h_ + 16384, (SB) + 2048);                                       \
        GLDS16(h_ + 17408, (SB) + 3072);                                       \
    } while (0)

#define LD_EI(GMT)                                                             \
    (*(const f32x4*)(wsA + (size_t)((GMT) >> 3) * REC_BYTES + 32768 +          \
                     ((GMT) & 7) * 64 + g * 16))

    // prologue: stage set 0 (flies under phase A/B)
    STAGE(wv, sA);
    f32x4 eiA = LD_EI(wv);

    // phase A: x tile -> LDS f32 [c][pos]
    {
        int p = tid & 63, cq = tid >> 6;
#pragma unroll
        for (int j = 0; j < 16; ++j) {
            int c = cq * 16 + j;
            xl[c * 65 + p] = xin[(size_t)c * SPATIAL + p];
        }
    }
    __syncthreads();

    // phase B: per-wave B-fragments (positions) hi/lo fp16
    half8 bh[4][2], bl[4][2];
#pragma unroll
    for (int t = 0; t < 4; ++t)
#pragma unroll
        for (int s = 0; s < 2; ++s) {
            int p = t * 16 + col;
#pragma unroll
            for (int i = 0; i < 8; ++i) {
                int c = s * 32 + g * 8 + i;
                float v = xl[c * 65 + p];
                _Float16 h = (_Float16)v;
                bh[t][s][i] = h;
                bl[t][s][i] = (_Float16)(v - (float)h);
            }
        }

    float best[4][4];
    int   bmt[4][4];                       // stores winning gmt (0..63)
#pragma unroll
    for (int t = 0; t < 4; ++t)
#pragma unroll
        for (int r = 0; r < 4; ++r) { best[t][r] = -3.402823466e38f; bmt[t][r] = 0; }

#define CONSUME(SB, EI, GMT) do {                                              \
        const char* sb_ = (SB) + (size_t)lane * 16;                            \
        half8 ah0 = *(const half8*)(sb_);                                      \
        half8 ah1 = *(const half8*)(sb_ + 1024);                               \
        half8 al0 = *(const half8*)(sb_ + 2048);                               \
        half8 al1 = *(const half8*)(sb_ + 3072);                               \
        _Pragma("unroll")                                                      \
        for (int t = 0; t < 4; ++t) {                                          \
            f32x4 a = (EI);                                                    \
            a = __builtin_amdgcn_mfma_f32_16x16x32_f16(ah0, bh[t][0], a, 0, 0, 0); \
            a = __builtin_amdgcn_mfma_f32_16x16x32_f16(ah1, bh[t][1], a, 0, 0, 0); \
            a = __builtin_amdgcn_mfma_f32_16x16x32_f16(ah0, bl[t][0], a, 0, 0, 0); \
            a = __builtin_amdgcn_mfma_f32_16x16x32_f16(ah1, bl[t][1], a, 0, 0, 0); \
            a = __builtin_amdgcn_mfma_f32_16x16x32_f16(al0, bh[t][0], a, 0, 0, 0); \
            a = __builtin_amdgcn_mfma_f32_16x16x32_f16(al1, bh[t][1], a, 0, 0, 0); \
            _Pragma("unroll")                                                  \
            for (int r = 0; r < 4; ++r)                                        \
                if (a[r] > best[t][r]) { best[t][r] = a[r]; bmt[t][r] = (GMT); } \
        }                                                                      \
    } while (0)

    // main loop: 16 sets as 8 double-buffered pairs; counted vmcnt keeps the
    // next set's 5 loads (4 gload_lds + ei) in flight across each consume.
#pragma unroll
    for (int ii = 0; ii < 8; ++ii) {
        const int gA = wv + 4 * (2 * ii);
        const int gB = wv + 4 * (2 * ii + 1);
        STAGE(gB, sB);
        f32x4 eiB = LD_EI(gB);
        asm volatile("s_waitcnt vmcnt(5)" ::: "memory");   // set A staged
        CONSUME(sA, eiA, gA);
        if (ii < 7) {
            const int gN = wv + 4 * (2 * ii + 2);
            STAGE(gN, sA);
            eiA = LD_EI(gN);
            asm volatile("s_waitcnt vmcnt(5)" ::: "memory"); // set B staged
        } else {
            asm volatile("s_waitcnt vmcnt(0)" ::: "memory"); // drain last set
        }
        CONSUME(sB, eiB, gB);
    }
#undef STAGE
#undef LD_EI
#undef CONSUME
#undef GLDS16

    // per-wave lex-reduce (score desc, k asc) -> LDS
#pragma unroll
    for (int t = 0; t < 4; ++t) {
        float bs = best[t][0];
        int   bk = bmt[t][0] * 16 + g * 4 + 0;
#pragma unroll
        for (int r = 1; r < 4; ++r) {
            float sc = best[t][r];
            int   k  = bmt[t][r] * 16 + g * 4 + r;
            if (sc > bs || (sc == bs && k < bk)) { bs = sc; bk = k; }
        }
#pragma unroll
        for (int m = 16; m <= 32; m <<= 1) {
            float os = __shfl_xor(bs, m);
            int   ok = __shfl_xor(bk, m);
            if (os > bs || (os == bs && ok < bk)) { bs = os; bk = ok; }
        }
        if (g == 0) { redS[wv][t][col] = bs; redK[wv][t][col] = bk; }
    }
    __syncthreads();

    // cross-wave reduce (wave 0), write indices coalesced, publish winners
    if (wv == 0) {
        int t = lane >> 4, c2 = lane & 15;
        float bs = redS[0][t][c2];
        int   bk = redK[0][t][c2];
#pragma unroll
        for (int w = 1; w < 4; ++w) {
            float sc = redS[w][t][c2];
            int   k  = redK[w][t][c2];
            if (sc > bs || (sc == bs && k < bk)) { bs = sc; bk = k; }
        }
        kwin[lane] = bk;
        out[OUT_IDX + p0 + lane] = (float)bk;
    }
    __syncthreads();

    // epilogue: coalesced q stores (lane = position), exact f32 x from LDS
    float lsum = 0.f;
    {
        int p = tid & 63, cq = tid >> 6;
        int kk = kwin[p];
        const float* eb = emb + (size_t)kk * CDIM;     // L1/L2 gather
        float* q = out + OUT_Q + (size_t)b * (CDIM * SPATIAL) + s0;
#pragma unroll
        for (int j = 0; j < 16; ++j) {
            int c = cq * 16 + j;
            float e = eb[c];
            float x = xl[c * 65 + p];
            float d = e - x;                           // stop_grad(q - x)
            lsum = fmaf(d, d, lsum);
            q[(size_t)c * SPATIAL + p] = x + d;        // straight-through
        }
    }
#pragma unroll
    for (int off = 32; off > 0; off >>= 1) lsum += __shfl_down(lsum, off);
    if (lane == 0) redS[wv][0][0] = lsum;
    __syncthreads();
    if (tid == 0) {
        float t = redS[0][0][0] + redS[1][0][0] + redS[2][0][0] + redS[3][0][0];
        atomicAdd(out + OUT_LOSS, t * (0.25f / (float)NEL));
    }
}

extern "C" void kernel_launch(void* const* d_in, const int* in_sizes, int n_in,
                              void* d_out, int out_size, void* d_ws, size_t ws_size,
                              hipStream_t stream) {
    const float* in  = (const float*)d_in[0];   // [2,64,32,32,32] f32
    const float* emb = (const float*)d_in[1];   // [1024,64] f32
    float* out = (float*)d_out;
    char*  ws  = (char*)d_ws;                   // 266,240 B used

    prep_emb<<<64, 256, 0, stream>>>(emb, ws, out);
    vq_kernel<<<NPOS / BPOS, 256, 0, stream>>>(in, emb, ws, out);
}

// Round 7
// 50.148 us; speedup vs baseline: 1.3961x; 1.3961x over previous
//
#include <hip/hip_runtime.h>
#include <stdint.h>

#define KCODES  1024
#define CDIM    64
#define SPATIAL 32768
#define NPOS    65536
#define NEL     4194304

// d_out layout (floats), outputs concatenated in reference return order
#define OUT_Q    0
#define OUT_LOSS 4194304
#define OUT_IDX  4194305
#define OUT_SUM  4259841
#define OUT_EMB  4260097

// ws: 32 sets x 8KB record {Ah0,Al0,Ah1,Al1,Ah2,Al2,Ah3,Al3} (1KB chunks),
// then ei[1024] f32 (-0.5*||e||^2) at EIOFF
#define NSET  32
#define SETB  8192
#define EIOFF 262144
#define BPOS  256

typedef _Float16 half8  __attribute__((ext_vector_type(8)));
typedef float    f32x4  __attribute__((ext_vector_type(4)));
typedef float    f32x16 __attribute__((ext_vector_type(16)));

// ---- prep: fragment-swizzle codebook (32x32x16 A-frags), ei, zero, passthrough ----
__global__ void prep_emb(const float* __restrict__ emb, char* __restrict__ ws,
                         float* __restrict__ out) {
    int gt = blockIdx.x * 256 + threadIdx.x;        // 64 blocks -> 0..16383
    if (gt == 0) out[OUT_LOSS] = 0.f;
    if (gt < 256) out[OUT_SUM + gt] = 0.f;
    {   // embedding passthrough (OUT_EMB odd offset -> scalar stores)
        float4 v = *(const float4*)(emb + (size_t)gt * 4);
        float* o = out + OUT_EMB + (size_t)gt * 4;
        o[0] = v.x; o[1] = v.y; o[2] = v.z; o[3] = v.w;
    }
    if (gt < 8192) {                                 // one (code, 8-ch octet) each
        int k = gt >> 3, oct = gt & 7;
        int set = k >> 5, row = k & 31;
        int ks = oct >> 1, hc = oct & 1;             // c = ks*16 + hc*8 + i
        const float* e = emb + (size_t)k * CDIM + oct * 8;
        char* rec = ws + (size_t)set * SETB;
        // A-frag layout: lane l = hc*32+row holds 8 fp16 at chunk + l*16
        _Float16* hi = (_Float16*)(rec + (ks * 2 + 0) * 1024 + (hc * 32 + row) * 16);
        _Float16* lo = (_Float16*)(rec + (ks * 2 + 1) * 1024 + (hc * 32 + row) * 16);
        float s2 = 0.f;
        half8 hv, lv;
#pragma unroll
        for (int i = 0; i < 8; ++i) {
            float v = e[i];
            s2 = fmaf(v, v, s2);
            _Float16 h = (_Float16)v;
            hv[i] = h;
            lv[i] = (_Float16)(v - (float)h);
        }
        *(half8*)hi = hv;
        *(half8*)lo = lv;
        s2 += __shfl_xor(s2, 1);                     // reduce over the octet group
        s2 += __shfl_xor(s2, 2);
        s2 += __shfl_xor(s2, 4);
        if (oct == 0) ((float*)(ws + EIOFF))[k] = -0.5f * s2;
    }
}

// async global->LDS, 16B per lane, dst = wave-uniform base + lane*16
#define GLDS16(GSRC, LDST)                                                     \
    __builtin_amdgcn_global_load_lds(                                          \
        (const __attribute__((address_space(1))) void*)(GSRC),                 \
        (__attribute__((address_space(3))) void*)(LDST), 16, 0, 0)

// ---- main VQ kernel ----
// Grid 256 x 512 thr (8 waves). Block owns 256 positions; wave owns 32 (one
// 32-col B tile). All waves scan ALL 1024 codes as 32 sets of 32 via
// mfma_f32_32x32x16_f16, fp16 2-way split (3 terms). Codebook sets staged
// once per block in LDS (dbuf, 1 global_load_lds per wave per set), one
// barrier + vmcnt(0) per set. Score = x.e - 0.5||e||^2, argmax == argmin.
__global__ __launch_bounds__(512, 2) void vq_kernel(
        const float* __restrict__ in, const float* __restrict__ emb,
        const char* __restrict__ wsA, float* __restrict__ out) {
    __shared__ __align__(16) char stg[2][SETB];      // 16 KB dbuf
    __shared__ float xl[CDIM * 129];                 // 33 KB x transpose tile
    __shared__ int   kwin[BPOS];
    __shared__ float lred[8];

    const int tid  = threadIdx.x;
    const int lane = tid & 63, wv = tid >> 6;        // 8 waves
    const int col  = lane & 31, h = lane >> 5;       // B col / code-row half
    const int p0   = blockIdx.x * BPOS;
    const int b    = p0 >> 15;                       // 256-tile never straddles batch
    const int s0   = p0 & 32767;
    const float* xin = in + (size_t)b * (CDIM * SPATIAL) + s0;
    const float* eiG = (const float*)(wsA + EIOFF);

    // stage set 0 early; drained by the pre-loop vmcnt(0)+barrier
    GLDS16(wsA + (size_t)wv * 1024 + lane * 16, &stg[0][0] + wv * 1024 + lane * 16);

    // ---- phase A/B in two halves of 128 positions (xl reused) ----
    half8 bh[4], bl[4];                              // 32 pos x 64 ch hi/lo = 32 VGPR
    for (int H = 0; H < 2; ++H) {
        {
            int p = tid & 127, cq = tid >> 7;
#pragma unroll
            for (int j = 0; j < 16; ++j) {
                int c = cq * 16 + j;
                xl[c * 129 + p] = xin[(size_t)c * SPATIAL + H * 128 + p];
            }
        }
        __syncthreads();
        if ((wv >> 2) == H) {                        // waves of this half build B-frags
            int pp = (wv & 3) * 32 + col;
#pragma unroll
            for (int ks = 0; ks < 4; ++ks)
#pragma unroll
                for (int j = 0; j < 8; ++j) {
                    int c = ks * 16 + h * 8 + j;     // B k-local = h*8+j (matches A)
                    float v = xl[c * 129 + pp];
                    _Float16 hh = (_Float16)v;
                    bh[ks][j] = hh;
                    bl[ks][j] = (_Float16)(v - (float)hh);
                }
        }
        if (H == 0) {
            __syncthreads();                         // xl free for overwrite
        } else {
            asm volatile("s_waitcnt vmcnt(0)" ::: "memory");   // set 0 staged
            __syncthreads();
        }
    }

    // ---- main loop: 32 sets, LDS dbuf, 1 barrier/set ----
    float best = -3.402823466e38f;
    int   bk   = 0;
#pragma unroll 2
    for (int it = 0; it < NSET; ++it) {
        char* cur = &stg[0][0] + (size_t)(it & 1) * SETB;
        if (it + 1 < NSET) {                         // each wave stages 1 KB of next set
            char* nxt = &stg[0][0] + (size_t)((it + 1) & 1) * SETB;
            GLDS16(wsA + (size_t)(it + 1) * SETB + wv * 1024 + lane * 16,
                   nxt + wv * 1024 + lane * 16);
        }
        // ei for this set (L1-hot; consumed only at fold -> full-iter slack)
        f32x4 ei0 = *(const f32x4*)(eiG + it * 32 + 0 * 8 + 4 * h);
        f32x4 ei1 = *(const f32x4*)(eiG + it * 32 + 1 * 8 + 4 * h);
        f32x4 ei2 = *(const f32x4*)(eiG + it * 32 + 2 * 8 + 4 * h);
        f32x4 ei3 = *(const f32x4*)(eiG + it * 32 + 3 * 8 + 4 * h);

        f32x16 acc;
#pragma unroll
        for (int q = 0; q < 16; ++q) acc[q] = 0.f;
        const char* ap = cur + (size_t)lane * 16;
#pragma unroll
        for (int ks = 0; ks < 4; ++ks) {
            half8 ah = *(const half8*)(ap + (ks * 2 + 0) * 1024);
            half8 al = *(const half8*)(ap + (ks * 2 + 1) * 1024);
            acc = __builtin_amdgcn_mfma_f32_32x32x16_f16(ah, bh[ks], acc, 0, 0, 0);
            acc = __builtin_amdgcn_mfma_f32_32x32x16_f16(ah, bl[ks], acc, 0, 0, 0);
            acc = __builtin_amdgcn_mfma_f32_32x32x16_f16(al, bh[ks], acc, 0, 0, 0);
        }
        // fold: row = (q&3) + 8*(q>>2) + 4h; k ascending in (it,m,r) -> lex ties
        int kb = it * 32 + 4 * h;
#pragma unroll
        for (int m = 0; m < 4; ++m) {
            f32x4 ev = (m == 0) ? ei0 : (m == 1) ? ei1 : (m == 2) ? ei2 : ei3;
#pragma unroll
            for (int r = 0; r < 4; ++r) {
                float sc = acc[m * 4 + r] + ev[r];
                if (sc > best) { best = sc; bk = kb + m * 8 + r; }
            }
        }
        asm volatile("s_waitcnt vmcnt(0)" ::: "memory");   // next set staged
        __syncthreads();
    }

    // ---- cross-h reduce (lex: score desc, k asc), publish winners ----
    {
        float os = __shfl_xor(best, 32);
        int   ok = __shfl_xor(bk, 32);
        if (os > best || (os == best && ok < bk)) { best = os; bk = ok; }
        if (lane < 32) {
            kwin[wv * 32 + col] = bk;
            out[OUT_IDX + p0 + wv * 32 + col] = (float)bk;
        }
    }
    __syncthreads();

    // ---- epilogue: coalesced q stores, exact f32 x re-read (L3-hot), loss ----
    float lsum = 0.f;
    {
        int p = tid & 255, cq = tid >> 8;
        int kk = kwin[p];
        const float* eb = emb + (size_t)kk * CDIM;
        float* q = out + OUT_Q + (size_t)b * (CDIM * SPATIAL) + s0;
#pragma unroll
        for (int j = 0; j < 32; ++j) {
            int c = cq * 32 + j;
            float x = xin[(size_t)c * SPATIAL + p];
            float e = eb[c];
            float d = e - x;                         // stop_grad(q - x)
            lsum = fmaf(d, d, lsum);
            q[(size_t)c * SPATIAL + p] = x + d;      // straight-through
        }
    }
#pragma unroll
    for (int off = 32; off > 0; off >>= 1) lsum += __shfl_down(lsum, off);
    if (lane == 0) lred[wv] = lsum;
    __syncthreads();
    if (tid == 0) {
        float t = 0.f;
#pragma unroll
        for (int w = 0; w < 8; ++w) t += lred[w];
        atomicAdd(out + OUT_LOSS, t * (0.25f / (float)NEL));
    }
}

extern "C" void kernel_launch(void* const* d_in, const int* in_sizes, int n_in,
                              void* d_out, int out_size, void* d_ws, size_t ws_size,
                              hipStream_t stream) {
    const float* in  = (const float*)d_in[0];   // [2,64,32,32,32] f32
    const float* emb = (const float*)d_in[1];   // [1024,64] f32
    float* out = (float*)d_out;
    char*  ws  = (char*)d_ws;                   // 266,240 B used

    prep_emb<<<64, 256, 0, stream>>>(emb, ws, out);
    vq_kernel<<<NPOS / BPOS, 512, 0, stream>>>(in, emb, ws, out);
}